// Round 1
// baseline (143.814 us; speedup 1.0000x reference)
//
#include <hip/hip_runtime.h>
#include <hip/hip_bf16.h>
#include <cstdint>
#include <cstddef>

#define NN 8192
#define FIN 256
#define FO 128

typedef float f32x4 __attribute__((ext_vector_type(4)));
typedef __bf16 bf16x8 __attribute__((ext_vector_type(8)));

__device__ __forceinline__ unsigned enc_f32(float f) {
  unsigned u = __float_as_uint(f);
  return (u & 0x80000000u) ? ~u : (u | 0x80000000u);
}
__device__ __forceinline__ float dec_f32(unsigned u) {
  unsigned b = (u & 0x80000000u) ? (u ^ 0x80000000u) : ~u;
  return __uint_as_float(b);
}

// ---------------- K1: h = x @ W  (8192x256 @ 256x128) ----------------
// 256 blocks x 256 threads, 32 rows/block. thread: r = t&31, cg = t>>5 (16 cols)
__global__ void k1_xw(const float* __restrict__ x, const float* __restrict__ W,
                      float* __restrict__ h, unsigned* __restrict__ enc) {
  __shared__ float xs[32 * 66];   // pad 66: banks (2r+kk)%32 -> 2-way (free)
  __shared__ float Ws[64 * 128];
  int t = threadIdx.x;
  int r0 = blockIdx.x * 32;
  if (blockIdx.x == 0 && t == 0) *enc = 0u;  // init for K2's atomicMax
  int r = t & 31, cg = t >> 5;
  float acc[16];
#pragma unroll
  for (int i = 0; i < 16; ++i) acc[i] = 0.f;
  for (int ko = 0; ko < 4; ++ko) {
    __syncthreads();
    {  // stage x tile: 32 rows x 64 k
      int rr = t >> 3, kc = (t & 7) * 8;
      const float2* src = (const float2*)(x + (size_t)(r0 + rr) * FIN + ko * 64 + kc);
      float2* dst = (float2*)&xs[rr * 66 + kc];
#pragma unroll
      for (int q = 0; q < 4; ++q) dst[q] = src[q];
    }
    {  // stage W tile: 64 k x 128 c
      int kk = t >> 2, q = t & 3;
      const float4* src = (const float4*)(W + (size_t)(ko * 64 + kk) * FO + q * 32);
      float4* dst = (float4*)&Ws[kk * 128 + q * 32];
#pragma unroll
      for (int i = 0; i < 8; ++i) dst[i] = src[i];
    }
    __syncthreads();
#pragma unroll 8
    for (int kk = 0; kk < 64; ++kk) {
      float xv = xs[r * 66 + kk];
      const float4* wr = (const float4*)&Ws[kk * 128 + cg * 16];
      float4 w0 = wr[0], w1 = wr[1], w2 = wr[2], w3 = wr[3];
      acc[0]  = fmaf(xv, w0.x, acc[0]);  acc[1]  = fmaf(xv, w0.y, acc[1]);
      acc[2]  = fmaf(xv, w0.z, acc[2]);  acc[3]  = fmaf(xv, w0.w, acc[3]);
      acc[4]  = fmaf(xv, w1.x, acc[4]);  acc[5]  = fmaf(xv, w1.y, acc[5]);
      acc[6]  = fmaf(xv, w1.z, acc[6]);  acc[7]  = fmaf(xv, w1.w, acc[7]);
      acc[8]  = fmaf(xv, w2.x, acc[8]);  acc[9]  = fmaf(xv, w2.y, acc[9]);
      acc[10] = fmaf(xv, w2.z, acc[10]); acc[11] = fmaf(xv, w2.w, acc[11]);
      acc[12] = fmaf(xv, w3.x, acc[12]); acc[13] = fmaf(xv, w3.y, acc[13]);
      acc[14] = fmaf(xv, w3.z, acc[14]); acc[15] = fmaf(xv, w3.w, acc[15]);
    }
  }
  float* hp = h + (size_t)(r0 + r) * FO + cg * 16;
#pragma unroll
  for (int i = 0; i < 4; ++i)
    ((float4*)hp)[i] = make_float4(acc[4 * i], acc[4 * i + 1], acc[4 * i + 2], acc[4 * i + 3]);
}

// ---------------- K2: hT_hi/lo (bf16 transpose), s1, s2, max(s2) ----------------
// 128 blocks x 256 threads, 64 rows/block
__global__ void k2_prep(const float* __restrict__ h, const float* __restrict__ a,
                        __bf16* __restrict__ hT_hi, __bf16* __restrict__ hT_lo,
                        float* __restrict__ s1, float* __restrict__ s2,
                        unsigned* __restrict__ enc) {
  __shared__ float ht[64 * 129];
  int t = threadIdx.x;
  int r0 = blockIdx.x * 64;
  {  // stage h tile 64x128
    int rr = t >> 2, q = t & 3;
    const float4* src = (const float4*)(h + (size_t)(r0 + rr) * FO + q * 32);
    float* dst = &ht[rr * 129 + q * 32];
#pragma unroll
    for (int i = 0; i < 8; ++i) {
      float4 v = src[i];
      dst[4 * i + 0] = v.x; dst[4 * i + 1] = v.y;
      dst[4 * i + 2] = v.z; dst[4 * i + 3] = v.w;
    }
  }
  __syncthreads();
  {  // transposed hi/lo bf16 write: thread covers (c = t>>1, 32 rows)
    int c = t >> 1, half = t & 1;
    alignas(16) unsigned short hi[32];
    alignas(16) unsigned short lo[32];
#pragma unroll
    for (int i = 0; i < 32; ++i) {
      float v = ht[(half * 32 + i) * 129 + c];
      __bf16 bh = (__bf16)v;
      float rr = v - (float)bh;
      __bf16 bl = (__bf16)rr;
      hi[i] = __builtin_bit_cast(unsigned short, bh);
      lo[i] = __builtin_bit_cast(unsigned short, bl);
    }
    int4* dh = (int4*)(hT_hi + (size_t)c * NN + r0 + half * 32);
    int4* dl = (int4*)(hT_lo + (size_t)c * NN + r0 + half * 32);
#pragma unroll
    for (int i = 0; i < 4; ++i) { dh[i] = ((const int4*)hi)[i]; dl[i] = ((const int4*)lo)[i]; }
  }
  if (t < 64) {  // s1/s2 per row + block max of s2 (wave 0 only)
    int row = r0 + t;
    float v1 = 0.f, v2 = 0.f;
#pragma unroll 16
    for (int c = 0; c < FO; ++c) {
      float hv = ht[t * 129 + c];
      v1 = fmaf(hv, a[c], v1);
      v2 = fmaf(hv, a[FO + c], v2);
    }
    s1[row] = v1; s2[row] = v2;
    float m = v2;
#pragma unroll
    for (int off = 1; off < 64; off <<= 1) m = fmaxf(m, __shfl_xor(m, off));
    if (t == 0) atomicMax(enc, enc_f32(m));
  }
}

// weight element: w = adj>0 ? exp(leaky(s1+s2) - m) : 0, rounded to bf16;
// sum accumulates the *rounded* weight for exact normalization consistency.
__device__ __forceinline__ __bf16 wel(int av, float s2v, float s1v, float mv, float& sum) {
  float tt = s1v + s2v;
  tt = tt > 0.f ? tt : 0.01f * tt;
  float wf = (av > 0) ? __expf(tt - mv) : 0.f;
  __bf16 wb = (__bf16)wf;
  sum += (float)wb;
  return wb;
}

// ---------------- K4: main fused attention x h (split-K) ----------------
// grid (64, splitk), 256 threads = 4 waves x 32 rows. MFMA 16x16x32 bf16.
// A (weights) computed directly in fragment layout: lane l -> row l&15, k 8*(l>>4)+e.
__global__ void __launch_bounds__(256) k4_main(
    const int* __restrict__ adj, const float* __restrict__ s1g,
    const float* __restrict__ s2g, const unsigned* __restrict__ enc,
    const __bf16* __restrict__ hT_hi, const __bf16* __restrict__ hT_lo,
    float* __restrict__ num_p, float* __restrict__ den_p, int jchunk) {
  __shared__ __bf16 Bhi[128 * 32];
  __shared__ __bf16 Blo[128 * 32];
  int t = threadIdx.x;
  int l = t & 63, wv = t >> 6;
  int r0 = blockIdx.x * 128;
  int split = blockIdx.y;
  int jbeg = split * jchunk;
  int l15 = l & 15, kgrp = l >> 4;
  int rowA0 = r0 + wv * 32 + l15;
  int rowA1 = rowA0 + 16;
  float c2 = dec_f32(*enc);
  float s10 = s1g[rowA0], s11 = s1g[rowA1];
  float m0 = s10 + c2; m0 = m0 > 0.f ? m0 : 0.01f * m0;
  float m1 = s11 + c2; m1 = m1 > 0.f ? m1 : 0.01f * m1;
  f32x4 acc[2][8];
#pragma unroll
  for (int a2 = 0; a2 < 2; ++a2)
#pragma unroll
    for (int cf = 0; cf < 8; ++cf) acc[a2][cf] = (f32x4){0.f, 0.f, 0.f, 0.f};
  float sum0 = 0.f, sum1 = 0.f;
  const int* adjr0 = adj + (size_t)rowA0 * NN;
  const int* adjr1 = adj + (size_t)rowA1 * NN;

  for (int j0 = jbeg; j0 < jbeg + jchunk; j0 += 32) {
    {  // stage hT tile (128 c x 32 j), two precisions
      int c = t >> 1, half = t & 1;
      const int4* sh = (const int4*)(hT_hi + (size_t)c * NN + j0 + half * 16);
      const int4* sl = (const int4*)(hT_lo + (size_t)c * NN + j0 + half * 16);
      int4* dh = (int4*)(Bhi + c * 32 + half * 16);
      int4* dl = (int4*)(Blo + c * 32 + half * 16);
      dh[0] = sh[0]; dh[1] = sh[1];
      dl[0] = sl[0]; dl[1] = sl[1];
    }
    int jl = j0 + kgrp * 8;
    const int4* ap0 = (const int4*)(adjr0 + jl);
    const int4* ap1 = (const int4*)(adjr1 + jl);
    int4 A00 = ap0[0], A01 = ap0[1];
    int4 A10 = ap1[0], A11 = ap1[1];
    float4 sa = *(const float4*)(s2g + jl);
    float4 sb = *(const float4*)(s2g + jl + 4);
    bf16x8 af0, af1;
    af0[0] = wel(A00.x, sa.x, s10, m0, sum0);
    af0[1] = wel(A00.y, sa.y, s10, m0, sum0);
    af0[2] = wel(A00.z, sa.z, s10, m0, sum0);
    af0[3] = wel(A00.w, sa.w, s10, m0, sum0);
    af0[4] = wel(A01.x, sb.x, s10, m0, sum0);
    af0[5] = wel(A01.y, sb.y, s10, m0, sum0);
    af0[6] = wel(A01.z, sb.z, s10, m0, sum0);
    af0[7] = wel(A01.w, sb.w, s10, m0, sum0);
    af1[0] = wel(A10.x, sa.x, s11, m1, sum1);
    af1[1] = wel(A10.y, sa.y, s11, m1, sum1);
    af1[2] = wel(A10.z, sa.z, s11, m1, sum1);
    af1[3] = wel(A10.w, sa.w, s11, m1, sum1);
    af1[4] = wel(A11.x, sb.x, s11, m1, sum1);
    af1[5] = wel(A11.y, sb.y, s11, m1, sum1);
    af1[6] = wel(A11.z, sb.z, s11, m1, sum1);
    af1[7] = wel(A11.w, sb.w, s11, m1, sum1);
    __syncthreads();
    const __bf16* bp_h = Bhi + l15 * 32 + kgrp * 8;
    const __bf16* bp_l = Blo + l15 * 32 + kgrp * 8;
#pragma unroll
    for (int cf = 0; cf < 8; ++cf) {
      bf16x8 bh = *(const bf16x8*)(bp_h + cf * 512);
      bf16x8 bl = *(const bf16x8*)(bp_l + cf * 512);
      acc[0][cf] = __builtin_amdgcn_mfma_f32_16x16x32_bf16(af0, bh, acc[0][cf], 0, 0, 0);
      acc[0][cf] = __builtin_amdgcn_mfma_f32_16x16x32_bf16(af0, bl, acc[0][cf], 0, 0, 0);
      acc[1][cf] = __builtin_amdgcn_mfma_f32_16x16x32_bf16(af1, bh, acc[1][cf], 0, 0, 0);
      acc[1][cf] = __builtin_amdgcn_mfma_f32_16x16x32_bf16(af1, bl, acc[1][cf], 0, 0, 0);
    }
    __syncthreads();
  }
  // full row sums (lanes l, l^16, l^32, l^48 share a row)
  sum0 += __shfl_xor(sum0, 16); sum0 += __shfl_xor(sum0, 32);
  sum1 += __shfl_xor(sum1, 16); sum1 += __shfl_xor(sum1, 32);
  size_t sbase = (size_t)split * NN;
  if (l < 16) {
    den_p[sbase + r0 + wv * 32 + l] = sum0;
    den_p[sbase + r0 + wv * 32 + 16 + l] = sum1;
  }
  // C/D layout: col = l&15, row = 4*(l>>4)+i
#pragma unroll
  for (int a2 = 0; a2 < 2; ++a2) {
#pragma unroll
    for (int cf = 0; cf < 8; ++cf) {
#pragma unroll
      for (int i = 0; i < 4; ++i) {
        int row = r0 + wv * 32 + a2 * 16 + kgrp * 4 + i;
        int col = cf * 16 + l15;
        num_p[(sbase + row) * (size_t)FO + col] = acc[a2][cf][i];
      }
    }
  }
}

// ---------------- K5: finalize out = elu(sum(num)/sum(den)) ----------------
__global__ void k5_fin(const float* __restrict__ num_p, const float* __restrict__ den_p,
                       float* __restrict__ out, int splitk) {
  int idx = blockIdx.x * 256 + threadIdx.x;
  int row = idx >> 7;
  float num = 0.f, den = 0.f;
  for (int s = 0; s < splitk; ++s) {
    num += num_p[(size_t)s * (NN * FO) + idx];
    den += den_p[(size_t)s * NN + row];
  }
  float v = num / den;
  out[idx] = v > 0.f ? v : expm1f(v);
}

extern "C" void kernel_launch(void* const* d_in, const int* in_sizes, int n_in,
                              void* d_out, int out_size, void* d_ws, size_t ws_size,
                              hipStream_t stream) {
  const float* x   = (const float*)d_in[0];
  const int*   adj = (const int*)d_in[1];
  const float* W   = (const float*)d_in[2];
  const float* a   = (const float*)d_in[3];
  float* out = (float*)d_out;
  char* ws = (char*)d_ws;

  float*    h     = (float*)ws;                                  // 4 MB
  __bf16*   hT_hi = (__bf16*)(ws + ((size_t)4 << 20));           // 2 MB
  __bf16*   hT_lo = (__bf16*)(ws + ((size_t)6 << 20));           // 2 MB
  float*    s1    = (float*)(ws + ((size_t)8 << 20));            // 32 KB
  float*    s2    = (float*)(ws + ((size_t)8 << 20) + (32u << 10));
  unsigned* enc   = (unsigned*)(ws + ((size_t)8 << 20) + (64u << 10));
  float*    den_p = (float*)(ws + ((size_t)8 << 20) + (128u << 10)); // 256 KB max
  float*    num_p = (float*)(ws + ((size_t)9 << 20));            // splitk * 4 MB

  int splitk = 8;
  while (splitk > 1 &&
         ((size_t)9 << 20) + (size_t)splitk * NN * FO * 4 > ws_size)
    splitk >>= 1;
  int jchunk = NN / splitk;

  k1_xw<<<dim3(256), dim3(256), 0, stream>>>(x, W, h, enc);
  k2_prep<<<dim3(128), dim3(256), 0, stream>>>(h, a, hT_hi, hT_lo, s1, s2, enc);
  k4_main<<<dim3(64, splitk), dim3(256), 0, stream>>>(adj, s1, s2, enc, hT_hi, hT_lo,
                                                      num_p, den_p, jchunk);
  k5_fin<<<dim3((NN * FO) / 256), dim3(256), 0, stream>>>(num_p, den_p, out, splitk);
}